// Round 4
// baseline (157.676 us; speedup 1.0000x reference)
//
#include <hip/hip_runtime.h>
#include <hip/hip_bf16.h>
#include <math.h>

#define NBOX   16384
#define NPRE   1024
#define NPOST  512
#define NMS_TH 0.8f
#define DEN_EPS 1e-8f
#define NCAND  2048          // top-k candidate buffer
#define NBUCK  8192          // 13-bit histogram buckets

typedef unsigned long long ull;

__device__ __forceinline__ unsigned mono_f32(float a) {
  unsigned u = __float_as_uint(a);
  return (u & 0x80000000u) ? ~u : (u | 0x80000000u);
}

// ---------------- K1: keys + histogram select + compact (one block/batch) ----
// key = (mono(score) << 14) | (16383 - i): u64 '>' == top_k order.
__global__ __launch_bounds__(1024) void k_hist(
    const float* __restrict__ cls, ull* __restrict__ cand,
    unsigned* __restrict__ candCount, unsigned* __restrict__ nz) {
  __shared__ unsigned hist[NBUCK];
  __shared__ unsigned wsuf[16];
  __shared__ unsigned thrT;
  __shared__ unsigned cnt;
  int b = blockIdx.x;
  int t = threadIdx.x;
  int lane = t & 63, wv = t >> 6;
  nz[b * NPRE + t] = 0u;                       // zero nz (mask is gated by nz)
#pragma unroll
  for (int k = 0; k < NBUCK / 1024; ++k) hist[t + k * 1024] = 0u;
  if (t == 0) cnt = 0u;
  __syncthreads();

  ull key[16];
#pragma unroll
  for (int k = 0; k < 16; ++k) {
    int i = k * 1024 + t;
    const float* cc = cls + ((size_t)b * NBOX + i) * 3;
    float s = fmaxf(cc[0], fmaxf(cc[1], cc[2]));
    unsigned u = mono_f32(s);
    key[k] = ((ull)u << 14) | (ull)(16383 - i);
    atomicAdd(&hist[u >> 19], 1u);
  }
  __syncthreads();

  // group-of-8 sums, then inclusive suffix scan: wave-level shfl + wave totals
  unsigned s8 = 0;
#pragma unroll
  for (int k = 0; k < 8; ++k) s8 += hist[t * 8 + k];
  unsigned v = s8;
#pragma unroll
  for (int off = 1; off < 64; off <<= 1) {
    unsigned o = __shfl_down(v, off, 64);
    if (lane + off < 64) v += o;
  }
  if (lane == 0) wsuf[wv] = v;                 // wave total (suffix incl wave)
  __syncthreads();
  if (t < 16) {
    unsigned x = wsuf[t];
#pragma unroll
    for (int off = 1; off < 16; off <<= 1) {
      unsigned o = __shfl_down(x, off, 64);
      if (t + off < 16) x += o;
    }
    wsuf[t] = x;                               // suffix over wave totals
  }
  __syncthreads();
  unsigned Sown = v + ((wv < 15) ? wsuf[wv + 1] : 0u);  // S[t] inclusive
  unsigned Snxt = Sown - s8;                             // S[t+1]
  if (Sown >= NPRE && Snxt < NPRE) {           // unique boundary group
    unsigned c = Snxt;
    unsigned T = t * 8;
    for (int k = 7; k >= 0; --k) {
      c += hist[t * 8 + k];
      if (c >= NPRE) { T = t * 8 + k; break; }
    }
    thrT = T;
  }
  __syncthreads();
  unsigned T = thrT;
#pragma unroll
  for (int k = 0; k < 16; ++k) {
    bool c = (unsigned)(key[k] >> 33) >= T;
    ull bal = __ballot(c);
    if (bal) {
      unsigned base = 0;
      if (lane == 0) base = atomicAdd(&cnt, (unsigned)__popcll(bal));
      base = (unsigned)__shfl((int)base, 0, 64);
      if (c) {
        unsigned pos = base + (unsigned)__popcll(bal & ((1ull << lane) - 1ull));
        if (pos < NCAND) cand[(size_t)b * NCAND + pos] = key[k];
      }
    }
  }
  __syncthreads();
  if (t == 0) candCount[b] = (cnt < NCAND) ? cnt : NCAND;
}

// ---------------- K2: rank candidates, emit topi + geometry ------------------
// binfo row (16 floats): x,y,dx,dy,cos,sin,cx[4],cy[4],circumrad,area
// pinfo[j] = float4(x, y, circumrad, area)  — coalesced cheap-test data
__global__ __launch_bounds__(256) void k_ranksel(
    const float* __restrict__ box, const ull* __restrict__ cand,
    const unsigned* __restrict__ candCount,
    int* __restrict__ topi, float* __restrict__ binfo, float4* __restrict__ pinfo) {
  __shared__ ull lk[NCAND];
  int b = blockIdx.y;
  int tid = threadIdx.x;
  int j = blockIdx.x * 256 + tid;              // 0..2047
  unsigned C = candCount[b];
#pragma unroll
  for (int k = 0; k < NCAND / 256; ++k) {
    int idx = k * 256 + tid;
    lk[idx] = ((unsigned)idx < C) ? cand[(size_t)b * NCAND + idx] : 0ULL;
  }
  __syncthreads();
  ull my = ((unsigned)j < C) ? lk[j] : 0ULL;
  int r = 0;
  const ulonglong2* p2 = (const ulonglong2*)lk;
#pragma unroll 8
  for (int k = 0; k < NCAND / 2; ++k) {
    ulonglong2 kk = p2[k];
    r += (kk.x > my) ? 1 : 0;
    r += (kk.y > my) ? 1 : 0;
  }
  if ((unsigned)j >= C || r >= NPRE) return;
  int i = 16383 - (int)(my & 0x3FFFULL);
  topi[b * NPRE + r] = i;
  const float* bp = box + ((size_t)b * NBOX + i) * 7;
  float x = bp[0], y = bp[1], dx = bp[3], dy = bp[4], ry = bp[6];
  float c = cosf(ry), s = sinf(ry);
  float* o = binfo + ((size_t)b * NPRE + r) * 16;
  o[0] = x; o[1] = y; o[2] = dx; o[3] = dy; o[4] = c; o[5] = s;
  const float offx[4] = {0.5f, -0.5f, -0.5f, 0.5f};
  const float offy[4] = {0.5f, 0.5f, -0.5f, -0.5f};
#pragma unroll
  for (int k = 0; k < 4; ++k) {
    float lx = dx * offx[k], ly = dy * offy[k];
    o[6 + k]  = x + lx * c - ly * s;
    o[10 + k] = y + lx * s + ly * c;
  }
  float rad = 0.5f * sqrtf(dx * dx + dy * dy);
  float area = dx * dy;
  o[14] = rad; o[15] = area;
  pinfo[(size_t)b * NPRE + r] = make_float4(x, y, rad, area);
}

// ---------------- exact rotated IoU > thresh, register-only ------------------
// Stable argsort by (angle, idx) == successor chain on key=(mono(ang)<<5)|idx;
// polygon area = sum of cross(p, succ(p)), wrap to global min key.
__device__ bool iou_exact_gt(const float* __restrict__ Ab, const float* __restrict__ Bb) {
  float ax = Ab[0], ay = Ab[1], bx = Bb[0], by = Bb[1];
  float aA = Ab[15], aB = Bb[15];
  float acx[4], acy[4], bcx[4], bcy[4];
#pragma unroll
  for (int k = 0; k < 4; ++k) {
    acx[k] = Ab[6 + k]; acy[k] = Ab[10 + k];
    bcx[k] = Bb[6 + k]; bcy[k] = Bb[10 + k];
  }
  float px[24], py[24];
  bool act[24];
#pragma unroll
  for (int p = 0; p < 4; ++p) {
    float A0x = acx[p], A0y = acy[p];
    float DAx = acx[(p + 1) & 3] - A0x, DAy = acy[(p + 1) & 3] - A0y;
#pragma unroll
    for (int q = 0; q < 4; ++q) {
      float B0x = bcx[q], B0y = bcy[q];
      float DBx = bcx[(q + 1) & 3] - B0x, DBy = bcy[(q + 1) & 3] - B0y;
      float den = DAx * DBy - DAy * DBx;
      float dxx = B0x - A0x, dyy = B0y - A0y;
      bool dok = fabsf(den) > DEN_EPS;
      float dens = dok ? den : 1.0f;
      float t = (dxx * DBy - dyy * DBx) / dens;
      float u = (dxx * DAy - dyy * DAx) / dens;
      int k = p * 4 + q;
      px[k] = A0x + t * DAx;
      py[k] = A0y + t * DAy;
      act[k] = dok && t >= 0.f && t <= 1.f && u >= 0.f && u <= 1.f;
    }
  }
  float cA = Ab[4], sA = Ab[5], cB = Bb[4], sB = Bb[5];
#pragma unroll
  for (int k = 0; k < 4; ++k) {       // corners of A in B
    float rx = acx[k] - bx, ry = acy[k] - by;
    float qx =  rx * cB + ry * sB, qy = -rx * sB + ry * cB;
    px[16 + k] = acx[k]; py[16 + k] = acy[k];
    act[16 + k] = (fabsf(qx) <= Bb[2] * 0.5f + 1e-5f) && (fabsf(qy) <= Bb[3] * 0.5f + 1e-5f);
  }
#pragma unroll
  for (int k = 0; k < 4; ++k) {       // corners of B in A
    float rx = bcx[k] - ax, ry = bcy[k] - ay;
    float qx =  rx * cA + ry * sA, qy = -rx * sA + ry * cA;
    px[20 + k] = bcx[k]; py[20 + k] = bcy[k];
    act[20 + k] = (fabsf(qx) <= Ab[2] * 0.5f + 1e-5f) && (fabsf(qy) <= Ab[3] * 0.5f + 1e-5f);
  }
  int cnt = 0; float sx = 0.f, sy = 0.f;
#pragma unroll
  for (int k = 0; k < 24; ++k)
    if (act[k]) { cnt++; sx += px[k]; sy += py[k]; }
  float fc = (float)(cnt > 1 ? cnt : 1);
  float cx0 = sx / fc, cy0 = sy / fc;
  ull key[24];
#pragma unroll
  for (int k = 0; k < 24; ++k) {
    float ang = atan2f(py[k] - cy0, px[k] - cx0);
    key[k] = act[k] ? ((((ull)mono_f32(ang)) << 5) | (ull)k) : ~0ull;
  }
  ull kmin = ~0ull; float fx = 0.f, fy = 0.f;
#pragma unroll
  for (int k = 0; k < 24; ++k) {
    bool lt = key[k] < kmin;
    kmin = lt ? key[k] : kmin;
    fx = lt ? px[k] : fx;
    fy = lt ? py[k] : fy;
  }
  float ssum = 0.f;
#pragma unroll
  for (int k = 0; k < 24; ++k) {
    ull myk = key[k];
    ull best = ~0ull; float nx = fx, ny = fy;   // default: wrap to first
#pragma unroll
    for (int j = 0; j < 24; ++j) {
      bool c = (key[j] > myk) && (key[j] < best);
      best = c ? key[j] : best;
      nx = c ? px[j] : nx;
      ny = c ? py[j] : ny;
    }
    float contrib = px[k] * ny - py[k] * nx;
    ssum += (myk != ~0ull) ? contrib : 0.f;
  }
  float inter = 0.5f * fabsf(ssum);
  float uni = aA + aB - inter;
  return inter / fmaxf(uni, 1e-6f) > NMS_TH;
}

// ---------------- K3: cheap rejects + exec-masked exact IoU -> ballot mask ---
__global__ __launch_bounds__(256) void k_pairs(
    const float* __restrict__ binfo, const float4* __restrict__ pinfo,
    ull* __restrict__ mask, unsigned* __restrict__ nz) {
  int wv = (blockIdx.x * 256 + threadIdx.x) >> 6;
  int lane = threadIdx.x & 63;
  int w = wv & 15;
  int i = (wv >> 4) & (NPRE - 1);
  int b = wv >> 14;
  if (w * 64 + 63 <= i) return;                // wave-uniform: all j <= i
  int j = w * 64 + lane;
  float4 pj = pinfo[(size_t)b * NPRE + j];     // coalesced 16B/lane
  float4 pi = pinfo[(size_t)b * NPRE + i];     // broadcast
  bool cand = false;
  if (j > i) {
    float ddx = pi.x - pj.x, ddy = pi.y - pj.y;
    float rr = pi.z + pj.z + 1e-3f;
    if (ddx * ddx + ddy * ddy <= rr * rr) {    // not provably disjoint
      float mn = fminf(pi.w, pj.w), mx = fmaxf(pi.w, pj.w);
      if (mn > NMS_TH * mx) cand = true;       // not provably iou<=0.8
    }
  }
  const float* base = binfo + (size_t)b * NPRE * 16;
  bool pred = cand && iou_exact_gt(base + (size_t)i * 16, base + (size_t)j * 16);
  ull bal = __ballot(pred);
  if (lane == 0 && bal) {
    mask[((size_t)b * NPRE + i) * 16 + w] = bal;   // overwrite; gated by nz
    atomicOr(&nz[b * NPRE + i], 1u << w);
  }
}

// ---------------- K4: sparse greedy NMS (wave 0) + compact + gather ----------
__global__ __launch_bounds__(1024) void k_final(
    const float* __restrict__ box, const float* __restrict__ cls,
    const int* __restrict__ topi, const ull* __restrict__ mask,
    const unsigned* __restrict__ nz, float* __restrict__ out, int B) {
  __shared__ ull remv_sh[16];
  int b = blockIdx.x;
  int p = threadIdx.x;                 // 0..1023
  int lane = p & 63, wid = p >> 6;

  if (wid == 0) {                      // wave 0: serial sparse greedy NMS
    ull rfr[16];
#pragma unroll
    for (int w = 0; w < 16; ++w) {
      unsigned vz = nz[b * NPRE + w * 64 + lane];
      rfr[w] = __ballot(vz != 0u);     // rows with any suppression bits
    }
    ull remv = 0;                      // lane w<16 holds remv word w
    for (int w = 0; w < 16; ++w) {
      ull bb = rfr[w];                 // wave-uniform
      while (bb) {
        int ii = __ffsll(bb) - 1;
        bb &= bb - 1;
        int row = w * 64 + ii;
        ull rw = __shfl(remv, w, 64);
        if (!((rw >> ii) & 1ULL)) {    // row alive -> apply its suppression
          unsigned nzi = nz[b * NPRE + row];
          ull m = 0;
          if (lane < 16 && ((nzi >> lane) & 1u))
            m = mask[((size_t)b * NPRE + row) * 16 + lane];
          remv |= m;
        }
      }
    }
    if (lane < 16) remv_sh[lane] = remv;
  }
  __syncthreads();

  ull rw = remv_sh[wid];
  int alive = ((rw >> lane) & 1ULL) ? 0 : 1;
  int v = alive;
#pragma unroll
  for (int off = 1; off < 64; off <<= 1) {
    int t = __shfl_up(v, off, 64);
    if (lane >= off) v += t;
  }
  __shared__ int wtot[16], woff[17];
  if (lane == 63) wtot[wid] = v;
  __syncthreads();
  if (p == 0) {
    int acc = 0;
    for (int t = 0; t < 16; ++t) { woff[t] = acc; acc += wtot[t]; }
    woff[16] = acc;
  }
  __syncthreads();
  int excl = v - alive + woff[wid];
  int total = woff[16];
  float* rois   = out;
  float* scores = out + (size_t)B * NPOST * 7;
  float* labels = scores + (size_t)B * NPOST;
  float* logits = labels + (size_t)B * NPOST;
  if (alive && excl < NPOST) {
    int s = excl;
    int orig = topi[b * NPRE + p];
    const float* bb = box + ((size_t)b * NBOX + orig) * 7;
    float* ro = rois + ((size_t)b * NPOST + s) * 7;
#pragma unroll
    for (int c = 0; c < 7; ++c) ro[c] = bb[c];
    const float* cc = cls + ((size_t)b * NBOX + orig) * 3;
    float l0 = cc[0], l1 = cc[1], l2 = cc[2];
    float m = fmaxf(l0, fmaxf(l1, l2));
    int lab = (l0 == m) ? 0 : ((l1 == m) ? 1 : 2);   // argmax: first max
    scores[b * NPOST + s] = m;
    labels[b * NPOST + s] = (float)(lab + 1);
    float* lg = logits + ((size_t)b * NPOST + s) * 3;
    lg[0] = l0; lg[1] = l1; lg[2] = l2;
  }
  if (p < NPOST && p >= total) {       // invalid slots: zeros, label 1
    float* ro = rois + ((size_t)b * NPOST + p) * 7;
#pragma unroll
    for (int c = 0; c < 7; ++c) ro[c] = 0.f;
    scores[b * NPOST + p] = 0.f;
    labels[b * NPOST + p] = 1.f;
    float* lg = logits + ((size_t)b * NPOST + p) * 3;
    lg[0] = 0.f; lg[1] = 0.f; lg[2] = 0.f;
  }
}

extern "C" void kernel_launch(void* const* d_in, const int* in_sizes, int n_in,
                              void* d_out, int out_size, void* d_ws, size_t ws_size,
                              hipStream_t stream) {
  const float* box = (const float*)d_in[0];
  const float* cls = (const float*)d_in[1];
  float* out = (float*)d_out;
  int B = in_sizes[0] / (NBOX * 7);    // == 2

  char* w = (char*)d_ws;
  size_t off = 0;
  ull* cand        = (ull*)(w + off);      off += (size_t)B * NCAND * sizeof(ull);
  unsigned* candCt = (unsigned*)(w + off); off += (size_t)B * sizeof(unsigned);
  int* topi        = (int*)(w + off);      off += (size_t)B * NPRE * sizeof(int);
  off = (off + 63) & ~(size_t)63;
  float* binfo     = (float*)(w + off);    off += (size_t)B * NPRE * 16 * sizeof(float);
  float4* pinfo    = (float4*)(w + off);   off += (size_t)B * NPRE * sizeof(float4);
  ull* mask        = (ull*)(w + off);      off += (size_t)B * NPRE * 16 * sizeof(ull);
  unsigned* nz     = (unsigned*)(w + off); off += (size_t)B * NPRE * sizeof(unsigned);
  (void)off; (void)ws_size; (void)out_size; (void)n_in;

  hipLaunchKernelGGL(k_hist,    dim3(B), dim3(1024), 0, stream, cls, cand, candCt, nz);
  hipLaunchKernelGGL(k_ranksel, dim3(NCAND / 256, B), dim3(256), 0, stream, box, cand, candCt, topi, binfo, pinfo);
  hipLaunchKernelGGL(k_pairs,   dim3(B * NPRE * 16 / 4), dim3(256), 0, stream, binfo, pinfo, mask, nz);
  hipLaunchKernelGGL(k_final,   dim3(B), dim3(1024), 0, stream, box, cls, topi, mask, nz, out, B);
}

// Round 5
// 132.354 us; speedup vs baseline: 1.1913x; 1.1913x over previous
//
#include <hip/hip_runtime.h>
#include <hip/hip_bf16.h>
#include <math.h>

#define NBOX   16384
#define NPRE   1024
#define NPOST  512
#define NMS_TH 0.8f
#define DEN_EPS 1e-8f
#define NCAND  2048          // top-k candidate buffer
#define NBUCK  8192          // 13-bit histogram buckets
#define WMAX   (1u << 20)    // max worklist entries

typedef unsigned long long ull;

__device__ __forceinline__ unsigned mono_f32(float a) {
  unsigned u = __float_as_uint(a);
  return (u & 0x80000000u) ? ~u : (u | 0x80000000u);
}

// ---------------- K1: keys + histogram select + compact (one block/batch) ----
// key = (mono(score) << 14) | (16383 - i): u64 '>' == top_k order.
__global__ __launch_bounds__(1024) void k_hist(
    const float* __restrict__ cls, ull* __restrict__ cand,
    unsigned* __restrict__ candCount, unsigned* __restrict__ nz,
    unsigned* __restrict__ wcnt) {
  __shared__ unsigned hist[NBUCK];
  __shared__ unsigned wsuf[16];
  __shared__ unsigned thrT;
  __shared__ unsigned cnt;
  int b = blockIdx.x;
  int t = threadIdx.x;
  int lane = t & 63, wv = t >> 6;
  nz[b * NPRE + t] = 0u;                       // zero nz (mask is gated by nz)
  if (b == 0 && t == 0) wcnt[0] = 0u;
#pragma unroll
  for (int k = 0; k < NBUCK / 1024; ++k) hist[t + k * 1024] = 0u;
  if (t == 0) cnt = 0u;
  __syncthreads();

  ull key[16];
#pragma unroll
  for (int k = 0; k < 16; ++k) {
    int i = k * 1024 + t;
    const float* cc = cls + ((size_t)b * NBOX + i) * 3;
    float s = fmaxf(cc[0], fmaxf(cc[1], cc[2]));
    unsigned u = mono_f32(s);
    key[k] = ((ull)u << 14) | (ull)(16383 - i);
    atomicAdd(&hist[u >> 19], 1u);
  }
  __syncthreads();

  // group-of-8 sums, then inclusive suffix scan: wave shfl + wave totals
  unsigned s8 = 0;
#pragma unroll
  for (int k = 0; k < 8; ++k) s8 += hist[t * 8 + k];
  unsigned v = s8;
#pragma unroll
  for (int off = 1; off < 64; off <<= 1) {
    unsigned o = __shfl_down(v, off, 64);
    if (lane + off < 64) v += o;
  }
  if (lane == 0) wsuf[wv] = v;
  __syncthreads();
  if (t < 16) {
    unsigned x = wsuf[t];
#pragma unroll
    for (int off = 1; off < 16; off <<= 1) {
      unsigned o = __shfl_down(x, off, 64);
      if (t + off < 16) x += o;
    }
    wsuf[t] = x;
  }
  __syncthreads();
  unsigned Sown = v + ((wv < 15) ? wsuf[wv + 1] : 0u);  // inclusive suffix S[t]
  unsigned Snxt = Sown - s8;                             // S[t+1]
  if (Sown >= NPRE && Snxt < NPRE) {           // unique boundary group
    unsigned c = Snxt;
    unsigned T = t * 8;
    for (int k = 7; k >= 0; --k) {
      c += hist[t * 8 + k];
      if (c >= NPRE) { T = t * 8 + k; break; }
    }
    thrT = T;
  }
  __syncthreads();
  unsigned T = thrT;
#pragma unroll
  for (int k = 0; k < 16; ++k) {
    bool c = (unsigned)(key[k] >> 33) >= T;
    ull bal = __ballot(c);
    if (bal) {
      unsigned base = 0;
      if (lane == 0) base = atomicAdd(&cnt, (unsigned)__popcll(bal));
      base = (unsigned)__shfl((int)base, 0, 64);
      if (c) {
        unsigned pos = base + (unsigned)__popcll(bal & ((1ull << lane) - 1ull));
        if (pos < NCAND) cand[(size_t)b * NCAND + pos] = key[k];
      }
    }
  }
  __syncthreads();
  if (t == 0) candCount[b] = (cnt < NCAND) ? cnt : NCAND;
}

// ---------------- K2: rank candidates, emit topi + geometry ------------------
// binfo row (16 floats): x,y,dx,dy,cos,sin,cx[4],cy[4],circumrad,area
// pinfo[j] = float4(x, y, circumrad, area)  — coalesced cheap-test data
__global__ __launch_bounds__(256) void k_ranksel(
    const float* __restrict__ box, const ull* __restrict__ cand,
    const unsigned* __restrict__ candCount,
    int* __restrict__ topi, float* __restrict__ binfo, float4* __restrict__ pinfo) {
  __shared__ ull lk[NCAND];
  int b = blockIdx.y;
  int tid = threadIdx.x;
  int j = blockIdx.x * 256 + tid;              // 0..2047
  unsigned C = candCount[b];
#pragma unroll
  for (int k = 0; k < NCAND / 256; ++k) {
    int idx = k * 256 + tid;
    lk[idx] = ((unsigned)idx < C) ? cand[(size_t)b * NCAND + idx] : 0ULL;
  }
  __syncthreads();
  ull my = ((unsigned)j < C) ? lk[j] : 0ULL;
  int r = 0;
  const ulonglong2* p2 = (const ulonglong2*)lk;
#pragma unroll 8
  for (int k = 0; k < NCAND / 2; ++k) {
    ulonglong2 kk = p2[k];
    r += (kk.x > my) ? 1 : 0;
    r += (kk.y > my) ? 1 : 0;
  }
  if ((unsigned)j >= C || r >= NPRE) return;
  int i = 16383 - (int)(my & 0x3FFFULL);
  topi[b * NPRE + r] = i;
  const float* bp = box + ((size_t)b * NBOX + i) * 7;
  float x = bp[0], y = bp[1], dx = bp[3], dy = bp[4], ry = bp[6];
  float c = cosf(ry), s = sinf(ry);
  float* o = binfo + ((size_t)b * NPRE + r) * 16;
  o[0] = x; o[1] = y; o[2] = dx; o[3] = dy; o[4] = c; o[5] = s;
  const float offx[4] = {0.5f, -0.5f, -0.5f, 0.5f};
  const float offy[4] = {0.5f, 0.5f, -0.5f, -0.5f};
#pragma unroll
  for (int k = 0; k < 4; ++k) {
    float lx = dx * offx[k], ly = dy * offy[k];
    o[6 + k]  = x + lx * c - ly * s;
    o[10 + k] = y + lx * s + ly * c;
  }
  float rad = 0.5f * sqrtf(dx * dx + dy * dy);
  float area = dx * dy;
  o[14] = rad; o[15] = area;
  pinfo[(size_t)b * NPRE + r] = make_float4(x, y, rad, area);
}

// ---------------- exact rotated IoU > thresh, register-only ------------------
// Stable argsort by (angle, idx) == successor chain on key=(mono(ang)<<5)|idx;
// polygon area = sum of cross(p, succ(p)), wrap to global min key.
__device__ bool iou_exact_gt(const float* __restrict__ Ab, const float* __restrict__ Bb) {
  float ax = Ab[0], ay = Ab[1], bx = Bb[0], by = Bb[1];
  float aA = Ab[15], aB = Bb[15];
  float acx[4], acy[4], bcx[4], bcy[4];
#pragma unroll
  for (int k = 0; k < 4; ++k) {
    acx[k] = Ab[6 + k]; acy[k] = Ab[10 + k];
    bcx[k] = Bb[6 + k]; bcy[k] = Bb[10 + k];
  }
  float px[24], py[24];
  bool act[24];
#pragma unroll
  for (int p = 0; p < 4; ++p) {
    float A0x = acx[p], A0y = acy[p];
    float DAx = acx[(p + 1) & 3] - A0x, DAy = acy[(p + 1) & 3] - A0y;
#pragma unroll
    for (int q = 0; q < 4; ++q) {
      float B0x = bcx[q], B0y = bcy[q];
      float DBx = bcx[(q + 1) & 3] - B0x, DBy = bcy[(q + 1) & 3] - B0y;
      float den = DAx * DBy - DAy * DBx;
      float dxx = B0x - A0x, dyy = B0y - A0y;
      bool dok = fabsf(den) > DEN_EPS;
      float dens = dok ? den : 1.0f;
      float t = (dxx * DBy - dyy * DBx) / dens;
      float u = (dxx * DAy - dyy * DAx) / dens;
      int k = p * 4 + q;
      px[k] = A0x + t * DAx;
      py[k] = A0y + t * DAy;
      act[k] = dok && t >= 0.f && t <= 1.f && u >= 0.f && u <= 1.f;
    }
  }
  float cA = Ab[4], sA = Ab[5], cB = Bb[4], sB = Bb[5];
#pragma unroll
  for (int k = 0; k < 4; ++k) {       // corners of A in B
    float rx = acx[k] - bx, ry = acy[k] - by;
    float qx =  rx * cB + ry * sB, qy = -rx * sB + ry * cB;
    px[16 + k] = acx[k]; py[16 + k] = acy[k];
    act[16 + k] = (fabsf(qx) <= Bb[2] * 0.5f + 1e-5f) && (fabsf(qy) <= Bb[3] * 0.5f + 1e-5f);
  }
#pragma unroll
  for (int k = 0; k < 4; ++k) {       // corners of B in A
    float rx = bcx[k] - ax, ry = bcy[k] - ay;
    float qx =  rx * cA + ry * sA, qy = -rx * sA + ry * cA;
    px[20 + k] = bcx[k]; py[20 + k] = bcy[k];
    act[20 + k] = (fabsf(qx) <= Ab[2] * 0.5f + 1e-5f) && (fabsf(qy) <= Ab[3] * 0.5f + 1e-5f);
  }
  int cnt = 0; float sx = 0.f, sy = 0.f;
#pragma unroll
  for (int k = 0; k < 24; ++k)
    if (act[k]) { cnt++; sx += px[k]; sy += py[k]; }
  float fc = (float)(cnt > 1 ? cnt : 1);
  float cx0 = sx / fc, cy0 = sy / fc;
  ull key[24];
#pragma unroll
  for (int k = 0; k < 24; ++k) {
    float ang = atan2f(py[k] - cy0, px[k] - cx0);
    key[k] = act[k] ? ((((ull)mono_f32(ang)) << 5) | (ull)k) : ~0ull;
  }
  ull kmin = ~0ull; float fx = 0.f, fy = 0.f;
#pragma unroll
  for (int k = 0; k < 24; ++k) {
    bool lt = key[k] < kmin;
    kmin = lt ? key[k] : kmin;
    fx = lt ? px[k] : fx;
    fy = lt ? py[k] : fy;
  }
  float ssum = 0.f;
#pragma unroll
  for (int k = 0; k < 24; ++k) {
    ull myk = key[k];
    ull best = ~0ull; float nx = fx, ny = fy;   // default: wrap to first
#pragma unroll
    for (int j = 0; j < 24; ++j) {
      bool c = (key[j] > myk) && (key[j] < best);
      best = c ? key[j] : best;
      nx = c ? px[j] : nx;
      ny = c ? py[j] : ny;
    }
    float contrib = px[k] * ny - py[k] * nx;
    ssum += (myk != ~0ull) ? contrib : 0.f;
  }
  float inter = 0.5f * fabsf(ssum);
  float uni = aA + aB - inter;
  return inter / fmaxf(uni, 1e-6f) > NMS_TH;
}

// ---------------- K3a: cheap rejects -> compact worklist + mask-word zero ----
__global__ __launch_bounds__(256) void k_pairs(
    const float* __restrict__ binfo, const float4* __restrict__ pinfo,
    unsigned* __restrict__ wl, unsigned* __restrict__ wcnt, unsigned wcap,
    ull* __restrict__ mask, unsigned* __restrict__ nz) {
  int wv = (blockIdx.x * 256 + threadIdx.x) >> 6;
  int lane = threadIdx.x & 63;
  int w = wv & 15;
  int i = (wv >> 4) & (NPRE - 1);
  int b = wv >> 14;
  if (w * 64 + 63 <= i) return;                // wave-uniform: all j <= i
  int j = w * 64 + lane;
  float4 pj = pinfo[(size_t)b * NPRE + j];     // coalesced 16B/lane
  float4 pi = pinfo[(size_t)b * NPRE + i];     // broadcast
  bool cand = false;
  if (j > i) {
    float ddx = pi.x - pj.x, ddy = pi.y - pj.y;
    float rr = pi.z + pj.z + 1e-3f;
    if (ddx * ddx + ddy * ddy <= rr * rr) {    // not provably disjoint
      float mn = fminf(pi.w, pj.w), mx = fmaxf(pi.w, pj.w);
      if (mn > NMS_TH * mx) cand = true;       // not provably iou<=0.8
    }
  }
  ull bal = __ballot(cand);
  if (!bal) return;
  if (lane == 0) mask[((size_t)b * NPRE + i) * 16 + w] = 0ull;  // pre-zero word
  unsigned baseOff = 0;
  if (lane == 0) baseOff = atomicAdd(wcnt, (unsigned)__popcll(bal));
  baseOff = (unsigned)__shfl((int)baseOff, 0, 64);
  if (cand) {
    unsigned off = baseOff + (unsigned)__popcll(bal & ((1ull << lane) - 1ull));
    if (off < wcap) {
      wl[off] = ((unsigned)b << 20) | ((unsigned)i << 10) | (unsigned)j;
    } else {                                   // overflow fallback (never hit)
      const float* base = binfo + (size_t)b * NPRE * 16;
      if (iou_exact_gt(base + (size_t)i * 16, base + (size_t)j * 16)) {
        atomicOr(&mask[((size_t)b * NPRE + i) * 16 + w], 1ull << lane);
        atomicOr(&nz[b * NPRE + i], 1u << w);
      }
    }
  }
}

// ---------------- K3b: exact IoU over dense worklist -------------------------
__global__ __launch_bounds__(256) void k_iou(
    const float* __restrict__ binfo, const unsigned* __restrict__ wl,
    const unsigned* __restrict__ wcnt, unsigned wcap,
    ull* __restrict__ mask, unsigned* __restrict__ nz) {
  unsigned n = wcnt[0];
  if (n > wcap) n = wcap;
  unsigned stride = gridDim.x * 256;
  for (unsigned t = blockIdx.x * 256 + threadIdx.x; t < n; t += stride) {
    unsigned pk = wl[t];
    unsigned b = pk >> 20, i = (pk >> 10) & 1023, j = pk & 1023;
    const float* base = binfo + (size_t)b * NPRE * 16;
    if (iou_exact_gt(base + (size_t)i * 16, base + (size_t)j * 16)) {
      atomicOr(&mask[((size_t)b * NPRE + i) * 16 + (j >> 6)], 1ull << (j & 63));
      atomicOr(&nz[b * NPRE + i], 1u << (j >> 6));
    }
  }
}

// ---------------- K4: sparse greedy NMS (wave 0) + compact + gather ----------
__global__ __launch_bounds__(1024) void k_final(
    const float* __restrict__ box, const float* __restrict__ cls,
    const int* __restrict__ topi, const ull* __restrict__ mask,
    const unsigned* __restrict__ nz, float* __restrict__ out, int B) {
  __shared__ ull remv_sh[16];
  int b = blockIdx.x;
  int p = threadIdx.x;                 // 0..1023
  int lane = p & 63, wid = p >> 6;

  if (wid == 0) {                      // wave 0: serial sparse greedy NMS
    ull rfr[16];
#pragma unroll
    for (int w = 0; w < 16; ++w) {
      unsigned vz = nz[b * NPRE + w * 64 + lane];
      rfr[w] = __ballot(vz != 0u);     // rows with any suppression bits
    }
    ull remv = 0;                      // lane w<16 holds remv word w
    for (int w = 0; w < 16; ++w) {
      ull bb = rfr[w];                 // wave-uniform
      while (bb) {
        int ii = __ffsll(bb) - 1;
        bb &= bb - 1;
        int row = w * 64 + ii;
        ull rw = __shfl(remv, w, 64);
        if (!((rw >> ii) & 1ULL)) {    // row alive -> apply its suppression
          unsigned nzi = nz[b * NPRE + row];
          ull m = 0;
          if (lane < 16 && ((nzi >> lane) & 1u))
            m = mask[((size_t)b * NPRE + row) * 16 + lane];
          remv |= m;
        }
      }
    }
    if (lane < 16) remv_sh[lane] = remv;
  }
  __syncthreads();

  ull rw = remv_sh[wid];
  int alive = ((rw >> lane) & 1ULL) ? 0 : 1;
  int v = alive;
#pragma unroll
  for (int off = 1; off < 64; off <<= 1) {
    int t = __shfl_up(v, off, 64);
    if (lane >= off) v += t;
  }
  __shared__ int wtot[16], woff[17];
  if (lane == 63) wtot[wid] = v;
  __syncthreads();
  if (p == 0) {
    int acc = 0;
    for (int t = 0; t < 16; ++t) { woff[t] = acc; acc += wtot[t]; }
    woff[16] = acc;
  }
  __syncthreads();
  int excl = v - alive + woff[wid];
  int total = woff[16];
  float* rois   = out;
  float* scores = out + (size_t)B * NPOST * 7;
  float* labels = scores + (size_t)B * NPOST;
  float* logits = labels + (size_t)B * NPOST;
  if (alive && excl < NPOST) {
    int s = excl;
    int orig = topi[b * NPRE + p];
    const float* bb = box + ((size_t)b * NBOX + orig) * 7;
    float* ro = rois + ((size_t)b * NPOST + s) * 7;
#pragma unroll
    for (int c = 0; c < 7; ++c) ro[c] = bb[c];
    const float* cc = cls + ((size_t)b * NBOX + orig) * 3;
    float l0 = cc[0], l1 = cc[1], l2 = cc[2];
    float m = fmaxf(l0, fmaxf(l1, l2));
    int lab = (l0 == m) ? 0 : ((l1 == m) ? 1 : 2);   // argmax: first max
    scores[b * NPOST + s] = m;
    labels[b * NPOST + s] = (float)(lab + 1);
    float* lg = logits + ((size_t)b * NPOST + s) * 3;
    lg[0] = l0; lg[1] = l1; lg[2] = l2;
  }
  if (p < NPOST && p >= total) {       // invalid slots: zeros, label 1
    float* ro = rois + ((size_t)b * NPOST + p) * 7;
#pragma unroll
    for (int c = 0; c < 7; ++c) ro[c] = 0.f;
    scores[b * NPOST + p] = 0.f;
    labels[b * NPOST + p] = 1.f;
    float* lg = logits + ((size_t)b * NPOST + p) * 3;
    lg[0] = 0.f; lg[1] = 0.f; lg[2] = 0.f;
  }
}

extern "C" void kernel_launch(void* const* d_in, const int* in_sizes, int n_in,
                              void* d_out, int out_size, void* d_ws, size_t ws_size,
                              hipStream_t stream) {
  const float* box = (const float*)d_in[0];
  const float* cls = (const float*)d_in[1];
  float* out = (float*)d_out;
  int B = in_sizes[0] / (NBOX * 7);    // == 2

  char* w = (char*)d_ws;
  size_t off = 0;
  ull* cand        = (ull*)(w + off);      off += (size_t)B * NCAND * sizeof(ull);
  unsigned* candCt = (unsigned*)(w + off); off += (size_t)B * sizeof(unsigned);
  int* topi        = (int*)(w + off);      off += (size_t)B * NPRE * sizeof(int);
  off = (off + 63) & ~(size_t)63;
  float* binfo     = (float*)(w + off);    off += (size_t)B * NPRE * 16 * sizeof(float);
  float4* pinfo    = (float4*)(w + off);   off += (size_t)B * NPRE * sizeof(float4);
  ull* mask        = (ull*)(w + off);      off += (size_t)B * NPRE * 16 * sizeof(ull);
  unsigned* nz     = (unsigned*)(w + off); off += (size_t)B * NPRE * sizeof(unsigned);
  unsigned* wcnt   = (unsigned*)(w + off); off += 64;
  unsigned* wl     = (unsigned*)(w + off);
  unsigned wcap = 0;
  if (ws_size > off) {
    size_t rem = (ws_size - off) / sizeof(unsigned);
    wcap = (rem < (size_t)WMAX) ? (unsigned)rem : WMAX;
  }
  (void)out_size; (void)n_in;

  hipLaunchKernelGGL(k_hist,    dim3(B), dim3(1024), 0, stream, cls, cand, candCt, nz, wcnt);
  hipLaunchKernelGGL(k_ranksel, dim3(NCAND / 256, B), dim3(256), 0, stream, box, cand, candCt, topi, binfo, pinfo);
  hipLaunchKernelGGL(k_pairs,   dim3(B * NPRE * 16 / 4), dim3(256), 0, stream, binfo, pinfo, wl, wcnt, wcap, mask, nz);
  hipLaunchKernelGGL(k_iou,     dim3(128), dim3(256), 0, stream, binfo, wl, wcnt, wcap, mask, nz);
  hipLaunchKernelGGL(k_final,   dim3(B), dim3(1024), 0, stream, box, cls, topi, mask, nz, out, B);
}